// Round 3
// baseline (425.335 us; speedup 1.0000x reference)
//
#include <hip/hip_runtime.h>
#include <hip/hip_fp16.h>

// Problem constants
#define BB    16
#define LL    48000
#define WW    64
#define LWT   512
#define NELEM (BB*LL)      // 768000
#define NGRP  (NELEM/4)    // 192000 groups of 4 elements
#define RATIO (512.0/16000.0)

#define KD_THREADS 512
#define KD_BLOCKS  512
#define KD_WAVES   (KD_BLOCKS * (KD_THREADS/64))       // 4096
#define GPW        ((NGRP + KD_WAVES - 1) / KD_WAVES)  // 47

#define EPT 47             // elements per thread in kScan (1024*47 >= 48000)

// ---------------- Kernel S: fused scan + pack + wavetable transpose --------
// Blocks 0..15: one block per row r. Each thread owns EPT consecutive
// elements: fp64 sequential sum -> block exclusive scan (wave shfl scan +
// LDS wave-combine) -> sequential emit of packed (idx<<23 | alpha_q23).
// Blocks 16..17: transpose wavetables -> fp16 tab[idx][w].
__global__ __launch_bounds__(1024) void kScan(const float* __restrict__ pitch,
                                              const float* __restrict__ wt,
                                              __half* __restrict__ tab,
                                              unsigned* __restrict__ packed) {
    int bid = blockIdx.x;
    int t = threadIdx.x;
    if (bid >= BB) {
        // wavetable transpose: 2 blocks * 1024 thr * 16 elems = 32768
        int base = (bid - BB) * 16384;
        #pragma unroll
        for (int i = 0; i < 16; i++) {
            int tid2 = base + i * 1024 + t;
            int idx = tid2 >> 6, w = tid2 & 63;
            tab[tid2] = __float2half(wt[w * LWT + idx]);
        }
        return;
    }
    const int r = bid;
    const int lane = t & 63, wv = t >> 6;
    int l0 = t * EPT;
    int l1 = l0 + EPT; if (l1 > LL) l1 = LL;
    bool act = (l0 < LL);

    // Pass 1: per-thread fp64 sum of increments
    double s = 0.0;
    if (act) {
        const float* p = pitch + (size_t)r * LL;
        for (int j = l0; j < l1; j++) s += RATIO * (double)p[j];
    }
    // wave-level inclusive scan
    double inc = s;
    for (int d = 1; d < 64; d <<= 1) {
        double u = __shfl_up(inc, d);
        if (lane >= d) inc += u;
    }
    __shared__ double wsum[16];
    if (lane == 63) wsum[wv] = inc;
    __syncthreads();
    double wb = 0.0;
    for (int i = 0; i < wv; i++) wb += wsum[i];
    if (!act) return;
    double running = wb + inc - s;     // exclusive prefix for this thread

    // Pass 2: emit packed index/alpha per element
    const float* prow = pitch + (size_t)r * LL;
    unsigned* orow = packed + (size_t)r * LL;
    for (int j = l0; j < l1; j++) {
        running += RATIO * (double)prow[j];          // inclusive cumsum at j
        double inc0 = RATIO * (double)pitch[j];      // row 0 increment at j
        double idx = running - inc0;
        double m = idx - floor(idx * (1.0 / 512.0)) * 512.0;
        if (m < 0.0) m += 512.0;
        if (512.0 - m < 1e-5) m = 0.0;
        double lowd = floor(m);
        double alpha = m - lowd;
        unsigned il = (unsigned)lowd;
        unsigned au = (unsigned)(alpha * 8388608.0 + 0.5);
        if (au > 0x7fffffu) au = 0x7fffffu;
        orow[j] = (il << 23) | au;
    }
}

// ---------------- Kernel D: main synthesis ---------------------------------
// wave handles 4 elements/iter: 16 lanes per element, lane covers 4 w's.
// 512 threads/block, 512 blocks -> exactly 2 blocks/CU (128 KB LDS),
// 16 waves/CU. 3-deep prefetch => ~48 KB HBM bytes in flight per CU.
__global__ __launch_bounds__(KD_THREADS) void kD(const float4* __restrict__ attn4,
                                                 const float* __restrict__ env,
                                                 const unsigned* __restrict__ packed,
                                                 const __half* __restrict__ tabG,
                                                 float* __restrict__ out) {
    __shared__ __half tab[LWT * WW];                // 65536 B exactly
    {
        const uint4* s4 = (const uint4*)tabG;
        uint4* d4 = (uint4*)tab;
        for (int i = threadIdx.x; i < (LWT * WW) / 8; i += KD_THREADS) d4[i] = s4[i];
    }
    __syncthreads();
    const int lane = threadIdx.x & 63;
    const int sub = lane >> 4;                      // element within group
    const int li  = lane & 15;                      // w-quad index
    const int wid = (blockIdx.x << 3) | (threadIdx.x >> 6);  // 0..4095
    int g0 = wid * GPW;
    int g1 = g0 + GPW;
    if (g1 > NGRP) g1 = NGRP;
    if (g0 >= g1) return;                           // after the only barrier
    const int gl = g1 - 1;

    // 3-deep software pipeline
    float4  a0 = attn4[(size_t)g0 * 64 + lane];
    unsigned p0 = packed[(g0 << 2) | sub];
    int ga = g0 + 1 <= gl ? g0 + 1 : gl;
    int gb = g0 + 2 <= gl ? g0 + 2 : gl;
    float4  a1 = attn4[(size_t)ga * 64 + lane];
    unsigned p1 = packed[(ga << 2) | sub];
    float4  a2 = attn4[(size_t)gb * 64 + lane];
    unsigned p2 = packed[(gb << 2) | sub];

    for (int g = g0; g < g1; ++g) {
        float4 ac = a0;
        unsigned pc = p0;
        a0 = a1; a1 = a2;
        p0 = p1; p1 = p2;
        int gn = g + 3;
        if (gn <= gl) {                             // keep 3 loads in flight
            a2 = attn4[(size_t)gn * 64 + lane];
            p2 = packed[(gn << 2) | sub];
        }
        unsigned il = pc >> 23;
        float alpha = (float)(pc & 0x7fffffu) * (1.0f / 8388608.0f);
        unsigned ih = (il + 1) & 511;
        uint2 lo = *(const uint2*)(tab + (il << 6) + (li << 2));
        uint2 hi = *(const uint2*)(tab + (ih << 6) + (li << 2));
        __half2 l01 = *(__half2*)&lo.x, l23 = *(__half2*)&lo.y;
        __half2 h01 = *(__half2*)&hi.x, h23 = *(__half2*)&hi.y;
        float2 fl01 = __half22float2(l01), fl23 = __half22float2(l23);
        float2 fh01 = __half22float2(h01), fh23 = __half22float2(h23);
        float w0 = fmaf(alpha, fh01.x - fl01.x, fl01.x);
        float w1 = fmaf(alpha, fh01.y - fl01.y, fl01.y);
        float w2 = fmaf(alpha, fh23.x - fl23.x, fl23.x);
        float w3 = fmaf(alpha, fh23.y - fl23.y, fl23.y);
        float s = w0 * ac.x + w1 * ac.y + w2 * ac.z + w3 * ac.w;
        s += __shfl_xor(s, 1);
        s += __shfl_xor(s, 2);
        s += __shfl_xor(s, 4);
        s += __shfl_xor(s, 8);
        if (li == 0) {
            int e = (g << 2) | sub;
            out[e] = s * env[e];
        }
    }
}

extern "C" void kernel_launch(void* const* d_in, const int* in_sizes, int n_in,
                              void* d_out, int out_size, void* d_ws, size_t ws_size,
                              hipStream_t stream) {
    (void)in_sizes; (void)n_in; (void)out_size; (void)ws_size;
    const float* pitch = (const float*)d_in[0];
    const float* env   = (const float*)d_in[1];
    const float* attn  = (const float*)d_in[2];
    const float* wt    = (const float*)d_in[3];
    float* out = (float*)d_out;

    char* ws = (char*)d_ws;
    __half*   tab    = (__half*)(ws);               // 65536 B
    unsigned* packed = (unsigned*)(ws + 65536);     // 3,072,000 B

    kScan<<<BB + 2, 1024, 0, stream>>>(pitch, wt, tab, packed);
    kD<<<KD_BLOCKS, KD_THREADS, 0, stream>>>((const float4*)attn, env, packed, tab, out);
}

// Round 4
// 290.271 us; speedup vs baseline: 1.4653x; 1.4653x over previous
//
#include <hip/hip_runtime.h>
#include <hip/hip_fp16.h>

// Problem constants
#define BB    16
#define LL    48000
#define WW    64
#define LWT   512
#define CHUNK 750          // elements per scan chunk
#define NCH   64           // chunks per row (64*750 = 48000)
#define NELEM (BB*LL)      // 768000
#define NGRP  (NELEM/4)    // 192000 groups of 4 elements
#define RATIO (512.0/16000.0)

#define KD_THREADS 512
#define KD_BLOCKS  512
#define KD_WAVES   (KD_BLOCKS * (KD_THREADS/64))       // 4096
#define GPW        ((NGRP + KD_WAVES - 1) / KD_WAVES)  // 47

// ---------------- Kernel A: fp64 partial sum per (row, chunk) --------------
// Blocks >= BB*NCH additionally perform the wavetable transpose.
__global__ void kA(const float* __restrict__ pitch, double* __restrict__ csum,
                   const float* __restrict__ wt, __half* __restrict__ tab) {
    int bid = blockIdx.x;
    if (bid >= BB * NCH) {
        // transpose wavetables -> fp16 [idx][w]: 128 blocks * 256 = 32768
        int tid = (bid - BB * NCH) * 256 + threadIdx.x;
        int idx = tid >> 6, w = tid & 63;
        tab[tid] = __float2half(wt[w * LWT + idx]);
        return;
    }
    int r = bid >> 6, c = bid & 63;
    int t = threadIdx.x;
    double s = 0.0;
    if (t < 250) {
        const float* p = pitch + r * LL + c * CHUNK + t * 3;
        s = RATIO * (double)p[0] + RATIO * (double)p[1] + RATIO * (double)p[2];
    }
    for (int d = 1; d < 64; d <<= 1) s += __shfl_xor(s, d);
    __shared__ double wsh[4];
    if ((t & 63) == 0) wsh[t >> 6] = s;
    __syncthreads();
    if (t == 0) csum[bid] = wsh[0] + wsh[1] + wsh[2] + wsh[3];
}

// ---------------- Kernel C: per-element index/alpha -> packed uint ---------
// kB folded in: wave 0 of each block reduces the preceding chunk sums of its
// row to get the chunk base (exclusive prefix over <=63 doubles).
__global__ void kC(const float* __restrict__ pitch,
                   const double* __restrict__ csum,
                   unsigned* __restrict__ packed) {
    int bid = blockIdx.x;                           // r*64 + c
    int r = bid >> 6, c = bid & 63;
    int t = threadIdx.x;
    int lane = t & 63, wv = t >> 6;
    int l = c * CHUNK + t * 3;                      // within-row position
    bool act = (t < 250);
    double i0 = 0.0, i1 = 0.0, i2 = 0.0;
    if (act) {
        const float* p = pitch + r * LL + l;
        i0 = RATIO * (double)p[0];
        i1 = RATIO * (double)p[1];
        i2 = RATIO * (double)p[2];
    }
    double c0 = i0, c1 = i0 + i1, c2 = c1 + i2;
    // block-exclusive scan of thread totals (c2)
    double inc = c2;
    for (int d = 1; d < 64; d <<= 1) {
        double u = __shfl_up(inc, d);
        if (lane >= d) inc += u;
    }
    __shared__ double wsum[4];
    __shared__ double cbs;
    if (lane == 63) wsum[wv] = inc;
    if (wv == 0) {
        // inline kB: sum of csum[r*64 + j] for j < c
        double v = (lane < c) ? csum[(bid & ~63) + lane] : 0.0;
        for (int d = 1; d < 64; d <<= 1) v += __shfl_xor(v, d);
        if (lane == 0) cbs = v;
    }
    __syncthreads();
    double wb = 0.0;
    for (int i = 0; i < wv; i++) wb += wsum[i];
    if (!act) return;
    double base = cbs + (wb + inc - c2);            // exclusive prefix of thread
    double pre[3] = {c0, c1, c2};
    for (int k = 0; k < 3; k++) {
        double inc0 = RATIO * (double)pitch[l + k]; // row 0 increment at same l
        double idx = base + pre[k] - inc0;
        // exact remainder with floor-division semantics (matches np.remainder)
        double m = idx - floor(idx * (1.0 / 512.0)) * 512.0;
        if (m < 0.0) m += 512.0;                    // safety
        if (512.0 - m < 1e-5) m = 0.0;
        double lowd = floor(m);
        double alpha = m - lowd;
        unsigned il = (unsigned)lowd;
        unsigned au = (unsigned)(alpha * 8388608.0 + 0.5);
        if (au > 0x7fffffu) au = 0x7fffffu;
        packed[r * LL + l + k] = (il << 23) | au;
    }
}

// ---------------- Kernel D: main synthesis ---------------------------------
// wave handles 4 elements/iter: 16 lanes per element, lane covers 4 w's.
// 512 threads/block, 512 blocks -> exactly 2 blocks/CU (128 KB LDS),
// 16 waves/CU. 3-deep prefetch => ~48 KB HBM bytes in flight per CU.
__global__ __launch_bounds__(KD_THREADS) void kD(const float4* __restrict__ attn4,
                                                 const float* __restrict__ env,
                                                 const unsigned* __restrict__ packed,
                                                 const __half* __restrict__ tabG,
                                                 float* __restrict__ out) {
    __shared__ __half tab[LWT * WW];                // 65536 B exactly
    {
        const uint4* s4 = (const uint4*)tabG;
        uint4* d4 = (uint4*)tab;
        for (int i = threadIdx.x; i < (LWT * WW) / 8; i += KD_THREADS) d4[i] = s4[i];
    }
    __syncthreads();
    const int lane = threadIdx.x & 63;
    const int sub = lane >> 4;                      // element within group
    const int li  = lane & 15;                      // w-quad index
    const int wid = (blockIdx.x << 3) | (threadIdx.x >> 6);  // 0..4095
    int g0 = wid * GPW;
    int g1 = g0 + GPW;
    if (g1 > NGRP) g1 = NGRP;
    if (g0 >= g1) return;                           // after the only barrier
    const int gl = g1 - 1;

    // 3-deep software pipeline
    float4  a0 = attn4[(size_t)g0 * 64 + lane];
    unsigned p0 = packed[(g0 << 2) | sub];
    int ga = g0 + 1 <= gl ? g0 + 1 : gl;
    int gb = g0 + 2 <= gl ? g0 + 2 : gl;
    float4  a1 = attn4[(size_t)ga * 64 + lane];
    unsigned p1 = packed[(ga << 2) | sub];
    float4  a2 = attn4[(size_t)gb * 64 + lane];
    unsigned p2 = packed[(gb << 2) | sub];

    for (int g = g0; g < g1; ++g) {
        float4 ac = a0;
        unsigned pc = p0;
        a0 = a1; a1 = a2;
        p0 = p1; p1 = p2;
        int gn = g + 3;
        if (gn <= gl) {                             // keep 3 loads in flight
            a2 = attn4[(size_t)gn * 64 + lane];
            p2 = packed[(gn << 2) | sub];
        }
        unsigned il = pc >> 23;
        float alpha = (float)(pc & 0x7fffffu) * (1.0f / 8388608.0f);
        unsigned ih = (il + 1) & 511;
        uint2 lo = *(const uint2*)(tab + (il << 6) + (li << 2));
        uint2 hi = *(const uint2*)(tab + (ih << 6) + (li << 2));
        __half2 l01 = *(__half2*)&lo.x, l23 = *(__half2*)&lo.y;
        __half2 h01 = *(__half2*)&hi.x, h23 = *(__half2*)&hi.y;
        float2 fl01 = __half22float2(l01), fl23 = __half22float2(l23);
        float2 fh01 = __half22float2(h01), fh23 = __half22float2(h23);
        float w0 = fmaf(alpha, fh01.x - fl01.x, fl01.x);
        float w1 = fmaf(alpha, fh01.y - fl01.y, fl01.y);
        float w2 = fmaf(alpha, fh23.x - fl23.x, fl23.x);
        float w3 = fmaf(alpha, fh23.y - fl23.y, fl23.y);
        float s = w0 * ac.x + w1 * ac.y + w2 * ac.z + w3 * ac.w;
        s += __shfl_xor(s, 1);
        s += __shfl_xor(s, 2);
        s += __shfl_xor(s, 4);
        s += __shfl_xor(s, 8);
        if (li == 0) {
            int e = (g << 2) | sub;
            out[e] = s * env[e];
        }
    }
}

extern "C" void kernel_launch(void* const* d_in, const int* in_sizes, int n_in,
                              void* d_out, int out_size, void* d_ws, size_t ws_size,
                              hipStream_t stream) {
    (void)in_sizes; (void)n_in; (void)out_size; (void)ws_size;
    const float* pitch = (const float*)d_in[0];
    const float* env   = (const float*)d_in[1];
    const float* attn  = (const float*)d_in[2];
    const float* wt    = (const float*)d_in[3];
    float* out = (float*)d_out;

    char* ws = (char*)d_ws;
    __half*   tab    = (__half*)(ws);               // 65536 B
    double*   csum   = (double*)(ws + 65536);       // 8192 B
    unsigned* packed = (unsigned*)(ws + 73728);     // 3,072,000 B

    kA<<<BB * NCH + 128, 256, 0, stream>>>(pitch, csum, wt, tab);
    kC<<<BB * NCH, 256, 0, stream>>>(pitch, csum, packed);
    kD<<<KD_BLOCKS, KD_THREADS, 0, stream>>>((const float4*)attn, env, packed, tab, out);
}

// Round 5
// 290.208 us; speedup vs baseline: 1.4656x; 1.0002x over previous
//
#include <hip/hip_runtime.h>
#include <hip/hip_fp16.h>

// Problem constants
#define BB    16
#define LL    48000
#define WW    64
#define LWT   512
#define CHUNK 750          // elements per scan chunk
#define NCH   64           // chunks per row (64*750 = 48000)
#define NELEM (BB*LL)      // 768000
#define NGRP  (NELEM/4)    // 192000 groups of 4 elements
#define RATIO (512.0/16000.0)

#define KD_THREADS 1024
#define KD_BLOCKS  256
#define KD_WAVES   (KD_BLOCKS * (KD_THREADS/64))       // 4096
#define GPW        ((NGRP + KD_WAVES - 1) / KD_WAVES)  // 47

// ---------------- Kernel A: fp64 partial sum per (row, chunk) --------------
// Blocks >= BB*NCH additionally perform the wavetable transpose.
__global__ void kA(const float* __restrict__ pitch, double* __restrict__ csum,
                   const float* __restrict__ wt, __half* __restrict__ tab) {
    int bid = blockIdx.x;
    if (bid >= BB * NCH) {
        // transpose wavetables -> fp16 [idx][w]: 128 blocks * 256 = 32768
        int tid = (bid - BB * NCH) * 256 + threadIdx.x;
        int idx = tid >> 6, w = tid & 63;
        tab[tid] = __float2half(wt[w * LWT + idx]);
        return;
    }
    int r = bid >> 6, c = bid & 63;
    int t = threadIdx.x;
    double s = 0.0;
    if (t < 250) {
        const float* p = pitch + r * LL + c * CHUNK + t * 3;
        s = RATIO * (double)p[0] + RATIO * (double)p[1] + RATIO * (double)p[2];
    }
    for (int d = 1; d < 64; d <<= 1) s += __shfl_xor(s, d);
    __shared__ double wsh[4];
    if ((t & 63) == 0) wsh[t >> 6] = s;
    __syncthreads();
    if (t == 0) csum[bid] = wsh[0] + wsh[1] + wsh[2] + wsh[3];
}

// ---------------- Kernel C: per-element index/alpha -> packed uint ---------
// kB folded in: wave 0 of each block reduces the preceding chunk sums of its
// row to get the chunk base (exclusive prefix over <=63 doubles).
__global__ void kC(const float* __restrict__ pitch,
                   const double* __restrict__ csum,
                   unsigned* __restrict__ packed) {
    int bid = blockIdx.x;                           // r*64 + c
    int r = bid >> 6, c = bid & 63;
    int t = threadIdx.x;
    int lane = t & 63, wv = t >> 6;
    int l = c * CHUNK + t * 3;                      // within-row position
    bool act = (t < 250);
    double i0 = 0.0, i1 = 0.0, i2 = 0.0;
    if (act) {
        const float* p = pitch + r * LL + l;
        i0 = RATIO * (double)p[0];
        i1 = RATIO * (double)p[1];
        i2 = RATIO * (double)p[2];
    }
    double c0 = i0, c1 = i0 + i1, c2 = c1 + i2;
    // block-exclusive scan of thread totals (c2)
    double inc = c2;
    for (int d = 1; d < 64; d <<= 1) {
        double u = __shfl_up(inc, d);
        if (lane >= d) inc += u;
    }
    __shared__ double wsum[4];
    __shared__ double cbs;
    if (lane == 63) wsum[wv] = inc;
    if (wv == 0) {
        // inline kB: sum of csum[r*64 + j] for j < c
        double v = (lane < c) ? csum[(bid & ~63) + lane] : 0.0;
        for (int d = 1; d < 64; d <<= 1) v += __shfl_xor(v, d);
        if (lane == 0) cbs = v;
    }
    __syncthreads();
    double wb = 0.0;
    for (int i = 0; i < wv; i++) wb += wsum[i];
    if (!act) return;
    double base = cbs + (wb + inc - c2);            // exclusive prefix of thread
    double pre[3] = {c0, c1, c2};
    for (int k = 0; k < 3; k++) {
        double inc0 = RATIO * (double)pitch[l + k]; // row 0 increment at same l
        double idx = base + pre[k] - inc0;
        // exact remainder with floor-division semantics (matches np.remainder)
        double m = idx - floor(idx * (1.0 / 512.0)) * 512.0;
        if (m < 0.0) m += 512.0;                    // safety
        if (512.0 - m < 1e-5) m = 0.0;
        double lowd = floor(m);
        double alpha = m - lowd;
        unsigned il = (unsigned)lowd;
        unsigned au = (unsigned)(alpha * 8388608.0 + 0.5);
        if (au > 0x7fffffu) au = 0x7fffffu;
        packed[r * LL + l + k] = (il << 23) | au;
    }
}

// ---------------- Kernel D: main synthesis ---------------------------------
// wave handles 4 elements/iter: 16 lanes per element, lane covers 4 w's.
// 1024 threads/block, 256 blocks -> 2 blocks/CU (128 KB LDS, 2048 thr),
// 32 waves/CU. __launch_bounds__(1024,8) caps VGPR at 64 to guarantee it.
// Prefetch issued BEFORE LDS staging so global loads overlap the tab copy.
__global__ __launch_bounds__(KD_THREADS, 8) void kD(const float4* __restrict__ attn4,
                                                    const float* __restrict__ env,
                                                    const unsigned* __restrict__ packed,
                                                    const __half* __restrict__ tabG,
                                                    float* __restrict__ out) {
    __shared__ __half tab[LWT * WW];                // 65536 B exactly
    const int lane = threadIdx.x & 63;
    const int sub = lane >> 4;                      // element within group
    const int li  = lane & 15;                      // w-quad index
    const int wid = (blockIdx.x << 4) | (threadIdx.x >> 6);  // 0..4095
    int g0 = wid * GPW;
    int g1 = g0 + GPW;
    if (g1 > NGRP) g1 = NGRP;
    const bool active = (g0 < g1);
    const int gl = active ? (g1 - 1) : (NGRP - 1);
    int gq0 = active ? g0 : (NGRP - 1);
    int ga = gq0 + 1 <= gl ? gq0 + 1 : gl;
    int gb = gq0 + 2 <= gl ? gq0 + 2 : gl;

    // 3-deep software pipeline — issue global loads first (overlap staging)
    float4  a0 = attn4[(size_t)gq0 * 64 + lane];
    unsigned p0 = packed[(gq0 << 2) | sub];
    float4  a1 = attn4[(size_t)ga * 64 + lane];
    unsigned p1 = packed[(ga << 2) | sub];
    float4  a2 = attn4[(size_t)gb * 64 + lane];
    unsigned p2 = packed[(gb << 2) | sub];

    {
        const uint4* s4 = (const uint4*)tabG;
        uint4* d4 = (uint4*)tab;
        for (int i = threadIdx.x; i < (LWT * WW) / 8; i += KD_THREADS) d4[i] = s4[i];
    }
    __syncthreads();
    if (!active) return;                            // after the only barrier

    for (int g = g0; g < g1; ++g) {
        float4 ac = a0;
        unsigned pc = p0;
        a0 = a1; a1 = a2;
        p0 = p1; p1 = p2;
        int gn = g + 3;
        if (gn <= gl) {                             // keep 3 loads in flight
            a2 = attn4[(size_t)gn * 64 + lane];
            p2 = packed[(gn << 2) | sub];
        }
        unsigned il = pc >> 23;
        float alpha = (float)(pc & 0x7fffffu) * (1.0f / 8388608.0f);
        unsigned ih = (il + 1) & 511;
        uint2 lo = *(const uint2*)(tab + (il << 6) + (li << 2));
        uint2 hi = *(const uint2*)(tab + (ih << 6) + (li << 2));
        __half2 l01 = *(__half2*)&lo.x, l23 = *(__half2*)&lo.y;
        __half2 h01 = *(__half2*)&hi.x, h23 = *(__half2*)&hi.y;
        float2 fl01 = __half22float2(l01), fl23 = __half22float2(l23);
        float2 fh01 = __half22float2(h01), fh23 = __half22float2(h23);
        float w0 = fmaf(alpha, fh01.x - fl01.x, fl01.x);
        float w1 = fmaf(alpha, fh01.y - fl01.y, fl01.y);
        float w2 = fmaf(alpha, fh23.x - fl23.x, fl23.x);
        float w3 = fmaf(alpha, fh23.y - fl23.y, fl23.y);
        float s = w0 * ac.x + w1 * ac.y + w2 * ac.z + w3 * ac.w;
        s += __shfl_xor(s, 1);
        s += __shfl_xor(s, 2);
        s += __shfl_xor(s, 4);
        s += __shfl_xor(s, 8);
        if (li == 0) {
            int e = (g << 2) | sub;
            out[e] = s * env[e];
        }
    }
}

extern "C" void kernel_launch(void* const* d_in, const int* in_sizes, int n_in,
                              void* d_out, int out_size, void* d_ws, size_t ws_size,
                              hipStream_t stream) {
    (void)in_sizes; (void)n_in; (void)out_size; (void)ws_size;
    const float* pitch = (const float*)d_in[0];
    const float* env   = (const float*)d_in[1];
    const float* attn  = (const float*)d_in[2];
    const float* wt    = (const float*)d_in[3];
    float* out = (float*)d_out;

    char* ws = (char*)d_ws;
    __half*   tab    = (__half*)(ws);               // 65536 B
    double*   csum   = (double*)(ws + 65536);       // 8192 B
    unsigned* packed = (unsigned*)(ws + 73728);     // 3,072,000 B

    kA<<<BB * NCH + 128, 256, 0, stream>>>(pitch, csum, wt, tab);
    kC<<<BB * NCH, 256, 0, stream>>>(pitch, csum, packed);
    kD<<<KD_BLOCKS, KD_THREADS, 0, stream>>>((const float4*)attn, env, packed, tab, out);
}